// Round 1
// baseline (394.370 us; speedup 1.0000x reference)
//
#include <hip/hip_runtime.h>
#include <stdint.h>

// ---- problem dims ----
#define NB   32
#define CIN  128
#define COUT 256
#define HH   56
#define WW   56
#define S1   (HH*WW)      // 3136
#define HO   28
#define WO   28
#define S2   (HO*WO)      // 784
#define NS1  (NB*S1)      // 100352
#define NS2  (NB*S2)      // 25088
#define TOT2 (NS2*COUT)   // 6422528
#define EPSV 1e-5

// ---- workspace layout (bytes) ----
constexpr size_t OFF_XBITS = 0;                         // NS1*8*4 = 3,211,264
constexpr size_t OFF_WB1   = OFF_XBITS + (size_t)NS1*8*4;
constexpr size_t OFF_WB3   = OFF_WB1 + 256*8*4;         // 8 KB
constexpr size_t OFF_WDW   = OFF_WB3 + 256*16*4;        // 16 KB
constexpr size_t OFF_SC1   = OFF_WDW + 4096;
constexpr size_t OFF_SH1   = OFF_SC1 + 1024;
constexpr size_t OFF_SC2   = OFF_SH1 + 1024;
constexpr size_t OFF_SH2   = OFF_SC2 + 1024;
constexpr size_t OFF_SC3   = OFF_SH2 + 1024;
constexpr size_t OFF_SH3   = OFF_SC3 + 1024;
constexpr size_t OFF_OUT1  = OFF_SH3 + 1024;            // NS1*COUT i8 = 25,690,112
constexpr size_t OFF_RES   = OFF_OUT1 + (size_t)NS1*COUT;       // f32 25,690,112
constexpr size_t OFF_OUT2  = OFF_RES + (size_t)TOT2*4;          // i8 6,422,528
constexpr size_t OFF_XB2   = OFF_OUT2 + (size_t)TOT2;           // NS2*16*4 = 1,605,632
constexpr size_t OFF_OUT3  = OFF_XB2 + (size_t)NS2*16*4;        // i16 12,845,056
// total ~75.5 MB

// ---------------- pack weights: bitplanes + dw signs ----------------
__global__ __launch_bounds__(64) void packw_kernel(
    const float* __restrict__ w1, const float* __restrict__ w3,
    const float* __restrict__ wdw,
    uint32_t* __restrict__ wb1, uint32_t* __restrict__ wb3,
    int8_t* __restrict__ wdws) {
  int co = blockIdx.x;
  int l  = threadIdx.x;
  // w1: 128 inputs = 2 ballots of 64
  for (int h = 0; h < 2; ++h) {
    float v = w1[(size_t)co*CIN + h*64 + l];
    unsigned long long bp = __ballot(v > 0.f);
    unsigned long long bn = __ballot(v < 0.f);
    if (l == 0) {
      wb1[co*8 + 2*h    ] = (uint32_t)bp;
      wb1[co*8 + 2*h + 1] = (uint32_t)(bp >> 32);
      wb1[co*8 + 4 + 2*h    ] = (uint32_t)bn;
      wb1[co*8 + 4 + 2*h + 1] = (uint32_t)(bn >> 32);
    }
  }
  // w3: 256 inputs = 4 ballots
  for (int h = 0; h < 4; ++h) {
    float v = w3[(size_t)co*COUT + h*64 + l];
    unsigned long long bp = __ballot(v > 0.f);
    unsigned long long bn = __ballot(v < 0.f);
    if (l == 0) {
      wb3[co*16 + 2*h    ] = (uint32_t)bp;
      wb3[co*16 + 2*h + 1] = (uint32_t)(bp >> 32);
      wb3[co*16 + 8 + 2*h    ] = (uint32_t)bn;
      wb3[co*16 + 8 + 2*h + 1] = (uint32_t)(bn >> 32);
    }
  }
  if (l < 9) {
    float v = wdw[co*9 + l];
    wdws[co*9 + l] = (int8_t)((v > 0.f) - (v < 0.f));
  }
}

// ---------------- pack x into bitplanes over C ----------------
// layout: xbits[m*8 + w] w=0..3 pos bits (c in [32w,32w+32)), w=4..7 neg bits
__global__ __launch_bounds__(256) void packx_kernel(
    const float* __restrict__ x, uint32_t* __restrict__ xbits) {
  int m = blockIdx.x*256 + threadIdx.x;     // m = n*S1 + hw
  int n = m / S1, hw = m % S1;
  size_t base = ((size_t)n*CIN)*S1 + hw;
  #pragma unroll
  for (int wdx = 0; wdx < 4; ++wdx) {
    uint32_t p = 0, q = 0;
    for (int j = 0; j < 32; ++j) {
      float v = x[base + (size_t)(wdx*32 + j)*S1];
      p |= (uint32_t)(v > 0.f) << j;
      q |= (uint32_t)(v < 0.f) << j;
    }
    xbits[(size_t)m*8 + wdx    ] = p;
    xbits[(size_t)m*8 + 4 + wdx] = q;
  }
}

// ---------------- residual: fp32 1x1 conv stride 2 ----------------
// block = 64 threads; tile = 256 m positions x 8 co
__global__ __launch_bounds__(64) void residual_kernel(
    const float* __restrict__ x, const float* __restrict__ wadj,
    float* __restrict__ res) {
  int lane = threadIdx.x;
  int co0 = blockIdx.y * 8;
  int mb  = blockIdx.x * 256;
  int nn[4], hw2[4];
  size_t xbase[4];
  #pragma unroll
  for (int k = 0; k < 4; ++k) {
    int m = mb + lane + 64*k;
    nn[k] = m / S2; hw2[k] = m % S2;
    int ho = hw2[k] / WO, wo = hw2[k] % WO;
    xbase[k] = ((size_t)nn[k]*CIN)*S1 + (size_t)(2*ho)*WW + 2*wo;
  }
  float acc[4][8];
  #pragma unroll
  for (int k = 0; k < 4; ++k)
    #pragma unroll
    for (int j = 0; j < 8; ++j) acc[k][j] = 0.f;

  for (int c = 0; c < CIN; ++c) {
    float wv[8];
    #pragma unroll
    for (int j = 0; j < 8; ++j) wv[j] = wadj[(size_t)(co0 + j)*CIN + c];
    float xv[4];
    #pragma unroll
    for (int k = 0; k < 4; ++k) xv[k] = x[xbase[k] + (size_t)c*S1];
    #pragma unroll
    for (int k = 0; k < 4; ++k)
      #pragma unroll
      for (int j = 0; j < 8; ++j) acc[k][j] = fmaf(xv[k], wv[j], acc[k][j]);
  }
  #pragma unroll
  for (int k = 0; k < 4; ++k)
    #pragma unroll
    for (int j = 0; j < 8; ++j)
      res[((size_t)nn[k]*COUT + co0 + j)*S2 + hw2[k]] = acc[k][j];
}

// ---------------- conv1: binary 1x1 via bitplane popcount ----------------
__global__ __launch_bounds__(256) void conv1_kernel(
    const uint32_t* __restrict__ xb, const uint32_t* __restrict__ wb,
    int8_t* __restrict__ out1) {
  int m = blockIdx.x*256 + threadIdx.x;
  int n = m / S1, hw = m % S1;
  const uint32_t* xw = xb + (size_t)m*8;
  uint32_t p0 = xw[0], p1 = xw[1], p2 = xw[2], p3 = xw[3];
  uint32_t q0 = xw[4], q1 = xw[5], q2 = xw[6], q3 = xw[7];
  int co0 = blockIdx.y * 32;
  size_t obase = ((size_t)n*COUT)*S1 + hw;
  #pragma unroll 4
  for (int co = co0; co < co0 + 32; ++co) {
    const uint32_t* w8 = wb + (size_t)co*8;
    uint32_t a0 = w8[0], a1 = w8[1], a2 = w8[2], a3 = w8[3];
    uint32_t b0 = w8[4], b1 = w8[5], b2 = w8[6], b3 = w8[7];
    int acc = __popc(p0&a0) + __popc(p1&a1) + __popc(p2&a2) + __popc(p3&a3)
            + __popc(q0&b0) + __popc(q1&b1) + __popc(q2&b2) + __popc(q3&b3)
            - __popc(p0&b0) - __popc(p1&b1) - __popc(p2&b2) - __popc(p3&b3)
            - __popc(q0&a0) - __popc(q1&a1) - __popc(q2&a2) - __popc(q3&a3);
    if (acc > 127) acc = 127;   // +128 would wrap int8; prob ~2^-128
    out1[obase + (size_t)co*S1] = (int8_t)acc;
  }
}

// ---------------- per-channel BN stats (int8 buffer) ----------------
__global__ __launch_bounds__(256) void stats_i8_kernel(
    const int8_t* __restrict__ buf, const float* __restrict__ a,
    const float* __restrict__ g, const float* __restrict__ b,
    float* __restrict__ scale, float* __restrict__ shift,
    int ns, int s_sp) {
  int co = blockIdx.x;
  float av = a[co];
  double sum = 0.0, sq = 0.0;
  int n4 = ns / 4;
  for (int i = threadIdx.x; i < n4; i += 256) {
    int flat = i*4;
    int n = flat / s_sp, hw = flat % s_sp;
    const char4 v = *reinterpret_cast<const char4*>(buf + (size_t)(n*COUT + co)*s_sp + hw);
    float f0 = (float)v.x, f1 = (float)v.y, f2 = (float)v.z, f3 = (float)v.w;
    float p0 = f0 > 0.f ? f0 : av*f0;
    float p1 = f1 > 0.f ? f1 : av*f1;
    float p2 = f2 > 0.f ? f2 : av*f2;
    float p3 = f3 > 0.f ? f3 : av*f3;
    sum += (double)p0 + (double)p1 + (double)p2 + (double)p3;
    sq  += (double)p0*p0 + (double)p1*p1 + (double)p2*p2 + (double)p3*p3;
  }
  __shared__ double sa[256], sb[256];
  int t = threadIdx.x;
  sa[t] = sum; sb[t] = sq; __syncthreads();
  for (int s = 128; s > 0; s >>= 1) {
    if (t < s) { sa[t] += sa[t+s]; sb[t] += sb[t+s]; }
    __syncthreads();
  }
  if (t == 0) {
    double mean = sa[0] / ns;
    double var  = sb[0] / ns - mean*mean;
    double rs   = 1.0 / sqrt(var + EPSV);
    float sc = (float)rs * g[co];
    scale[co] = sc;
    shift[co] = b[co] - (float)mean * sc;
  }
}

__global__ __launch_bounds__(256) void stats_i16_kernel(
    const int16_t* __restrict__ buf, const float* __restrict__ a,
    const float* __restrict__ g, const float* __restrict__ b,
    float* __restrict__ scale, float* __restrict__ shift,
    int ns, int s_sp) {
  int co = blockIdx.x;
  float av = a[co];
  double sum = 0.0, sq = 0.0;
  for (int i = threadIdx.x; i < ns; i += 256) {
    int n = i / s_sp, hw = i % s_sp;
    float f = (float)buf[(size_t)(n*COUT + co)*s_sp + hw];
    float p = f > 0.f ? f : av*f;
    sum += p; sq += (double)p*p;
  }
  __shared__ double sa[256], sb[256];
  int t = threadIdx.x;
  sa[t] = sum; sb[t] = sq; __syncthreads();
  for (int s = 128; s > 0; s >>= 1) {
    if (t < s) { sa[t] += sa[t+s]; sb[t] += sb[t+s]; }
    __syncthreads();
  }
  if (t == 0) {
    double mean = sa[0] / ns;
    double var  = sb[0] / ns - mean*mean;
    double rs   = 1.0 / sqrt(var + EPSV);
    float sc = (float)rs * g[co];
    scale[co] = sc;
    shift[co] = b[co] - (float)mean * sc;
  }
}

// ---------------- depthwise 3x3 s2 p1 on sign(BN1(prelu(out1))) ----------------
__global__ __launch_bounds__(256) void dw_kernel(
    const int8_t* __restrict__ out1, const int8_t* __restrict__ wdws,
    const float* __restrict__ a1, const float* __restrict__ sc1,
    const float* __restrict__ sh1, int8_t* __restrict__ out2) {
  int idx = blockIdx.x*256 + threadIdx.x;   // over TOT2
  int hw2 = idx % S2;
  int nc  = idx / S2;           // n*COUT + co
  int co  = nc % COUT;
  int ho = hw2 / WO, wo = hw2 % WO;
  float av = a1[co], sc = sc1[co], sh = sh1[co];
  const int8_t* src = out1 + (size_t)nc * S1;
  int acc = 0;
  #pragma unroll
  for (int kh = 0; kh < 3; ++kh) {
    int ih = 2*ho - 1 + kh;
    if (ih < 0 || ih >= HH) continue;
    #pragma unroll
    for (int kw = 0; kw < 3; ++kw) {
      int iw = 2*wo - 1 + kw;
      if (iw < 0 || iw >= WW) continue;
      float f = (float)src[ih*WW + iw];
      float p = f > 0.f ? f : av*f;
      float tv = p*sc + sh;
      int s = (tv > 0.f) - (tv < 0.f);
      acc += s * (int)wdws[co*9 + kh*3 + kw];
    }
  }
  out2[idx] = (int8_t)acc;
}

// ---------------- pack sign(BN2(prelu(out2))) into bitplanes over C ----------------
__global__ __launch_bounds__(256) void pack2_kernel(
    const int8_t* __restrict__ out2, const float* __restrict__ a2,
    const float* __restrict__ sc2, const float* __restrict__ sh2,
    uint32_t* __restrict__ xb2) {
  int m = blockIdx.x*256 + threadIdx.x;   // n*S2 + hw
  int n = m / S2, hw = m % S2;
  #pragma unroll
  for (int wdx = 0; wdx < 8; ++wdx) {
    uint32_t p = 0, q = 0;
    for (int j = 0; j < 32; ++j) {
      int c = wdx*32 + j;
      float f = (float)out2[(size_t)(n*COUT + c)*S2 + hw];
      float pr = f > 0.f ? f : a2[c]*f;
      float tv = pr*sc2[c] + sh2[c];
      p |= (uint32_t)(tv > 0.f) << j;
      q |= (uint32_t)(tv < 0.f) << j;
    }
    xb2[(size_t)m*16 + wdx    ] = p;
    xb2[(size_t)m*16 + 8 + wdx] = q;
  }
}

// ---------------- conv3: binary 1x1 256->256 ----------------
__global__ __launch_bounds__(256) void conv3_kernel(
    const uint32_t* __restrict__ xb2, const uint32_t* __restrict__ wb3,
    int16_t* __restrict__ out3) {
  int m = blockIdx.x*256 + threadIdx.x;   // NS2
  int n = m / S2, hw = m % S2;
  const uint32_t* xw = xb2 + (size_t)m*16;
  uint32_t P[8], Q[8];
  #pragma unroll
  for (int i = 0; i < 8; ++i) { P[i] = xw[i]; Q[i] = xw[8+i]; }
  int co0 = blockIdx.y * 32;
  size_t obase = ((size_t)n*COUT)*S2 + hw;
  #pragma unroll 2
  for (int co = co0; co < co0 + 32; ++co) {
    const uint32_t* w = wb3 + (size_t)co*16;
    int acc = 0;
    #pragma unroll
    for (int i = 0; i < 8; ++i) {
      uint32_t wp = w[i], wn = w[8+i];
      acc += __popc(P[i]&wp) + __popc(Q[i]&wn) - __popc(P[i]&wn) - __popc(Q[i]&wp);
    }
    out3[obase + (size_t)co*S2] = (int16_t)acc;
  }
}

// ---------------- final: BN3(prelu(out3)) + residual ----------------
__global__ __launch_bounds__(256) void final_kernel(
    const int16_t* __restrict__ out3, const float* __restrict__ res,
    const float* __restrict__ a3, const float* __restrict__ sc3,
    const float* __restrict__ sh3, float* __restrict__ out) {
  int idx = blockIdx.x*256 + threadIdx.x;
  int co = (idx / S2) % COUT;
  float f = (float)out3[idx];
  float p = f > 0.f ? f : a3[co]*f;
  float t = p*sc3[co] + sh3[co];
  out[idx] = t + res[idx];
}

extern "C" void kernel_launch(void* const* d_in, const int* in_sizes, int n_in,
                              void* d_out, int out_size, void* d_ws, size_t ws_size,
                              hipStream_t stream) {
  (void)in_sizes; (void)n_in; (void)out_size; (void)ws_size;
  const float* x    = (const float*)d_in[0];
  const float* w1   = (const float*)d_in[1];
  const float* a1   = (const float*)d_in[2];
  const float* g1   = (const float*)d_in[3];
  const float* b1   = (const float*)d_in[4];
  const float* wdw  = (const float*)d_in[5];
  const float* a2   = (const float*)d_in[6];
  const float* g2   = (const float*)d_in[7];
  const float* b2   = (const float*)d_in[8];
  const float* w3   = (const float*)d_in[9];
  const float* a3   = (const float*)d_in[10];
  const float* g3   = (const float*)d_in[11];
  const float* b3   = (const float*)d_in[12];
  const float* wadj = (const float*)d_in[13];
  float* out = (float*)d_out;

  char* ws = (char*)d_ws;
  uint32_t* xbits = (uint32_t*)(ws + OFF_XBITS);
  uint32_t* wb1   = (uint32_t*)(ws + OFF_WB1);
  uint32_t* wb3   = (uint32_t*)(ws + OFF_WB3);
  int8_t*   wdws  = (int8_t*)  (ws + OFF_WDW);
  float*    sc1   = (float*)   (ws + OFF_SC1);
  float*    sh1   = (float*)   (ws + OFF_SH1);
  float*    sc2   = (float*)   (ws + OFF_SC2);
  float*    sh2   = (float*)   (ws + OFF_SH2);
  float*    sc3   = (float*)   (ws + OFF_SC3);
  float*    sh3   = (float*)   (ws + OFF_SH3);
  int8_t*   out1  = (int8_t*)  (ws + OFF_OUT1);
  float*    res   = (float*)   (ws + OFF_RES);
  int8_t*   out2  = (int8_t*)  (ws + OFF_OUT2);
  uint32_t* xb2   = (uint32_t*)(ws + OFF_XB2);
  int16_t*  out3  = (int16_t*) (ws + OFF_OUT3);

  packw_kernel<<<256, 64, 0, stream>>>(w1, w3, wdw, wb1, wb3, wdws);
  packx_kernel<<<NS1/256, 256, 0, stream>>>(x, xbits);
  residual_kernel<<<dim3(NS2/256, COUT/8), 64, 0, stream>>>(x, wadj, res);
  conv1_kernel<<<dim3(NS1/256, 8), 256, 0, stream>>>(xbits, wb1, out1);
  stats_i8_kernel<<<256, 256, 0, stream>>>(out1, a1, g1, b1, sc1, sh1, NS1, S1);
  dw_kernel<<<TOT2/256, 256, 0, stream>>>(out1, wdws, a1, sc1, sh1, out2);
  stats_i8_kernel<<<256, 256, 0, stream>>>(out2, a2, g2, b2, sc2, sh2, NS2, S2);
  pack2_kernel<<<NS2/256, 256, 0, stream>>>(out2, a2, sc2, sh2, xb2);
  conv3_kernel<<<dim3(NS2/256, 8), 256, 0, stream>>>(xb2, wb3, out3);
  stats_i16_kernel<<<256, 256, 0, stream>>>(out3, a3, g3, b3, sc3, sh3, NS2, S2);
  final_kernel<<<TOT2/256, 256, 0, stream>>>(out3, res, a3, sc3, sh3, out);
}

// Round 2
// 260.517 us; speedup vs baseline: 1.5138x; 1.5138x over previous
//
#include <hip/hip_runtime.h>
#include <stdint.h>

// ---- problem dims ----
#define NB   32
#define CIN  128
#define COUT 256
#define HH   56
#define WW   56
#define S1   (HH*WW)      // 3136
#define HO   28
#define WO   28
#define S2   (HO*WO)      // 784
#define NS1  (NB*S1)      // 100352
#define NS2  (NB*S2)      // 25088
#define TOT2 (NS2*COUT)   // 6422528
#define EPSV 1e-5f

// ---- workspace layout (bytes) ----
constexpr size_t OFF_XBITS = 0;                                 // NS1*8*4 = 3,211,264
constexpr size_t OFF_WB1   = OFF_XBITS + (size_t)NS1*8*4;       // 8 KB
constexpr size_t OFF_WB3   = OFF_WB1 + 256*8*4;                 // 16 KB
constexpr size_t OFF_WDW   = OFF_WB3 + 256*16*4;                // 4 KB
constexpr size_t OFF_ACC   = OFF_WDW + 4096;                    // 3*256*4 int = 12 KB
constexpr size_t OFF_OUT1  = OFF_ACC + 3*256*4*sizeof(int);     // NS1*COUT i8 = 25,690,112
constexpr size_t OFF_RES   = OFF_OUT1 + (size_t)NS1*COUT;       // f32 25,690,112
constexpr size_t OFF_OUT2  = OFF_RES + (size_t)TOT2*4;          // i8 6,422,528
constexpr size_t OFF_XB2   = OFF_OUT2 + (size_t)TOT2;           // NS2*16*4 = 1,605,632
constexpr size_t OFF_OUT3  = OFF_XB2 + (size_t)NS2*16*4;        // i16 12,845,056
// total ~75.6 MB

// finalize BN scale/shift from exact integer sums of prelu output
__device__ __forceinline__ void bn_finalize(const int* __restrict__ acc4,
                                            float a, float g, float b, float inv_ns,
                                            float& sc, float& sh) {
  float ps = (float)acc4[0];   // sum of v where v>0   (exact, <2^24)
  float ng = (float)acc4[1];   // sum of v where v<0
  float pq = (float)acc4[2];   // sum of v^2 where v>0
  float nq = (float)acc4[3];   // sum of v^2 where v<0
  float mean = (ps + a*ng) * inv_ns;
  float ex2  = (pq + a*a*nq) * inv_ns;
  float var  = ex2 - mean*mean;
  float rs   = rsqrtf(var + EPSV);
  sc = rs * g;
  sh = b - mean * sc;
}

// ---------------- pack weights: bitplanes + dw signs ----------------
__global__ __launch_bounds__(64) void packw_kernel(
    const float* __restrict__ w1, const float* __restrict__ w3,
    const float* __restrict__ wdw,
    uint32_t* __restrict__ wb1, uint32_t* __restrict__ wb3,
    int8_t* __restrict__ wdws) {
  int co = blockIdx.x;
  int l  = threadIdx.x;
  for (int h = 0; h < 2; ++h) {
    float v = w1[(size_t)co*CIN + h*64 + l];
    unsigned long long bp = __ballot(v > 0.f);
    unsigned long long bn = __ballot(v < 0.f);
    if (l == 0) {
      wb1[co*8 + 2*h    ] = (uint32_t)bp;
      wb1[co*8 + 2*h + 1] = (uint32_t)(bp >> 32);
      wb1[co*8 + 4 + 2*h    ] = (uint32_t)bn;
      wb1[co*8 + 4 + 2*h + 1] = (uint32_t)(bn >> 32);
    }
  }
  for (int h = 0; h < 4; ++h) {
    float v = w3[(size_t)co*COUT + h*64 + l];
    unsigned long long bp = __ballot(v > 0.f);
    unsigned long long bn = __ballot(v < 0.f);
    if (l == 0) {
      wb3[co*16 + 2*h    ] = (uint32_t)bp;
      wb3[co*16 + 2*h + 1] = (uint32_t)(bp >> 32);
      wb3[co*16 + 8 + 2*h    ] = (uint32_t)bn;
      wb3[co*16 + 8 + 2*h + 1] = (uint32_t)(bn >> 32);
    }
  }
  if (l < 9) {
    float v = wdw[co*9 + l];
    wdws[co*9 + l] = (int8_t)((v > 0.f) - (v < 0.f));
  }
}

// ---------------- pack x into bitplanes over C (split over wdx) ----------------
__global__ __launch_bounds__(256) void packx_kernel(
    const float* __restrict__ x, uint32_t* __restrict__ xbits) {
  int m = blockIdx.x*256 + threadIdx.x;     // m = n*S1 + hw
  int wdx = blockIdx.y;                     // 0..3
  int n = m / S1, hw = m % S1;
  size_t base = ((size_t)n*CIN + wdx*32)*S1 + hw;
  uint32_t p = 0, q = 0;
  #pragma unroll
  for (int j = 0; j < 32; ++j) {
    float v = x[base + (size_t)j*S1];
    p |= (uint32_t)(v > 0.f) << j;
    q |= (uint32_t)(v < 0.f) << j;
  }
  xbits[(size_t)m*8 + wdx    ] = p;
  xbits[(size_t)m*8 + 4 + wdx] = q;
}

// ---------------- residual: fp32 1x1 conv stride 2 ----------------
__global__ __launch_bounds__(64) void residual_kernel(
    const float* __restrict__ x, const float* __restrict__ wadj,
    float* __restrict__ res) {
  int lane = threadIdx.x;
  int co0 = blockIdx.y * 8;
  int mb  = blockIdx.x * 256;
  int nn[4], hw2[4];
  size_t xbase[4];
  #pragma unroll
  for (int k = 0; k < 4; ++k) {
    int m = mb + lane + 64*k;
    nn[k] = m / S2; hw2[k] = m % S2;
    int ho = hw2[k] / WO, wo = hw2[k] % WO;
    xbase[k] = ((size_t)nn[k]*CIN)*S1 + (size_t)(2*ho)*WW + 2*wo;
  }
  float acc[4][8];
  #pragma unroll
  for (int k = 0; k < 4; ++k)
    #pragma unroll
    for (int j = 0; j < 8; ++j) acc[k][j] = 0.f;

  for (int c = 0; c < CIN; ++c) {
    float wv[8];
    #pragma unroll
    for (int j = 0; j < 8; ++j) wv[j] = wadj[(size_t)(co0 + j)*CIN + c];
    float xv[4];
    #pragma unroll
    for (int k = 0; k < 4; ++k) xv[k] = x[xbase[k] + (size_t)c*S1];
    #pragma unroll
    for (int k = 0; k < 4; ++k)
      #pragma unroll
      for (int j = 0; j < 8; ++j) acc[k][j] = fmaf(xv[k], wv[j], acc[k][j]);
  }
  #pragma unroll
  for (int k = 0; k < 4; ++k)
    #pragma unroll
    for (int j = 0; j < 8; ++j)
      res[((size_t)nn[k]*COUT + co0 + j)*S2 + hw2[k]] = acc[k][j];
}

// ---------------- conv1: binary 1x1 via bitplane popcount ----------------
__global__ __launch_bounds__(256) void conv1_kernel(
    const uint32_t* __restrict__ xb, const uint32_t* __restrict__ wb,
    int8_t* __restrict__ out1) {
  int m = blockIdx.x*256 + threadIdx.x;
  int n = m / S1, hw = m % S1;
  const uint32_t* xw = xb + (size_t)m*8;
  uint32_t p0 = xw[0], p1 = xw[1], p2 = xw[2], p3 = xw[3];
  uint32_t q0 = xw[4], q1 = xw[5], q2 = xw[6], q3 = xw[7];
  int co0 = blockIdx.y * 32;
  size_t obase = ((size_t)n*COUT)*S1 + hw;
  #pragma unroll 4
  for (int co = co0; co < co0 + 32; ++co) {
    const uint32_t* w8 = wb + (size_t)co*8;
    uint32_t a0 = w8[0], a1 = w8[1], a2 = w8[2], a3 = w8[3];
    uint32_t b0 = w8[4], b1 = w8[5], b2 = w8[6], b3 = w8[7];
    int acc = __popc(p0&a0) + __popc(p1&a1) + __popc(p2&a2) + __popc(p3&a3)
            + __popc(q0&b0) + __popc(q1&b1) + __popc(q2&b2) + __popc(q3&b3)
            - __popc(p0&b0) - __popc(p1&b1) - __popc(p2&b2) - __popc(p3&b3)
            - __popc(q0&a0) - __popc(q1&a1) - __popc(q2&a2) - __popc(q3&a3);
    if (acc > 127) acc = 127;   // +128 would wrap int8; prob ~2^-128
    out1[obase + (size_t)co*S1] = (int8_t)acc;
  }
}

// ---------------- per-channel integer stats (int8 buffer) ----------------
// accumulates {sum v>0, sum v<0, sum v^2>0, sum v^2<0} as int32 (exact)
__global__ __launch_bounds__(256) void stats_i8_kernel(
    const int8_t* __restrict__ buf, int* __restrict__ accum,
    int s_sp, int quads_per_block) {
  int co = blockIdx.x, slice = blockIdx.y;
  int q0 = slice * quads_per_block;
  int psum = 0, nsum = 0, psq = 0, nsq = 0;
  for (int i = threadIdx.x; i < quads_per_block; i += 256) {
    int flat = (q0 + i) * 4;
    int n = flat / s_sp, hw = flat % s_sp;
    char4 v = *reinterpret_cast<const char4*>(buf + (size_t)(n*COUT + co)*s_sp + hw);
    int vs[4] = {v.x, v.y, v.z, v.w};
    #pragma unroll
    for (int k = 0; k < 4; ++k) {
      int f = vs[k];
      if (f > 0) { psum += f; psq += f*f; } else { nsum += f; nsq += f*f; }
    }
  }
  __shared__ int r0[256], r1[256], r2[256], r3[256];
  int t = threadIdx.x;
  r0[t] = psum; r1[t] = nsum; r2[t] = psq; r3[t] = nsq;
  __syncthreads();
  for (int s = 128; s > 0; s >>= 1) {
    if (t < s) { r0[t]+=r0[t+s]; r1[t]+=r1[t+s]; r2[t]+=r2[t+s]; r3[t]+=r3[t+s]; }
    __syncthreads();
  }
  if (t == 0) {
    atomicAdd(&accum[co*4+0], r0[0]);
    atomicAdd(&accum[co*4+1], r1[0]);
    atomicAdd(&accum[co*4+2], r2[0]);
    atomicAdd(&accum[co*4+3], r3[0]);
  }
}

__global__ __launch_bounds__(256) void stats_i16_kernel(
    const int16_t* __restrict__ buf, int* __restrict__ accum,
    int s_sp, int pairs_per_block) {
  int co = blockIdx.x, slice = blockIdx.y;
  int p0i = slice * pairs_per_block;
  int psum = 0, nsum = 0, psq = 0, nsq = 0;
  for (int i = threadIdx.x; i < pairs_per_block; i += 256) {
    int flat = (p0i + i) * 2;
    int n = flat / s_sp, hw = flat % s_sp;
    short2 v = *reinterpret_cast<const short2*>(buf + (size_t)(n*COUT + co)*s_sp + hw);
    int vs[2] = {v.x, v.y};
    #pragma unroll
    for (int k = 0; k < 2; ++k) {
      int f = vs[k];
      if (f > 0) { psum += f; psq += f*f; } else { nsum += f; nsq += f*f; }
    }
  }
  __shared__ int r0[256], r1[256], r2[256], r3[256];
  int t = threadIdx.x;
  r0[t] = psum; r1[t] = nsum; r2[t] = psq; r3[t] = nsq;
  __syncthreads();
  for (int s = 128; s > 0; s >>= 1) {
    if (t < s) { r0[t]+=r0[t+s]; r1[t]+=r1[t+s]; r2[t]+=r2[t+s]; r3[t]+=r3[t+s]; }
    __syncthreads();
  }
  if (t == 0) {
    atomicAdd(&accum[co*4+0], r0[0]);
    atomicAdd(&accum[co*4+1], r1[0]);
    atomicAdd(&accum[co*4+2], r2[0]);
    atomicAdd(&accum[co*4+3], r3[0]);
  }
}

// ---------------- depthwise 3x3 s2 p1 on sign(BN1(prelu(out1))) ----------------
__global__ __launch_bounds__(256) void dw_kernel(
    const int8_t* __restrict__ out1, const int8_t* __restrict__ wdws,
    const float* __restrict__ a1, const float* __restrict__ g1,
    const float* __restrict__ b1, const int* __restrict__ acc1,
    int8_t* __restrict__ out2) {
  int idx = blockIdx.x*256 + threadIdx.x;   // over TOT2
  int hw2 = idx % S2;
  int nc  = idx / S2;           // n*COUT + co
  int co  = nc % COUT;
  int ho = hw2 / WO, wo = hw2 % WO;
  float av = a1[co], sc, sh;
  bn_finalize(acc1 + co*4, av, g1[co], b1[co], 1.f/NS1, sc, sh);
  const int8_t* src = out1 + (size_t)nc * S1;
  int acc = 0;
  #pragma unroll
  for (int kh = 0; kh < 3; ++kh) {
    int ih = 2*ho - 1 + kh;
    if (ih < 0 || ih >= HH) continue;
    #pragma unroll
    for (int kw = 0; kw < 3; ++kw) {
      int iw = 2*wo - 1 + kw;
      if (iw < 0 || iw >= WW) continue;
      float f = (float)src[ih*WW + iw];
      float p = f > 0.f ? f : av*f;
      float tv = p*sc + sh;
      int s = (tv > 0.f) - (tv < 0.f);
      acc += s * (int)wdws[co*9 + kh*3 + kw];
    }
  }
  out2[idx] = (int8_t)acc;
}

// ---------------- pack sign(BN2(prelu(out2))), split over wdx ----------------
__global__ __launch_bounds__(256) void pack2_kernel(
    const int8_t* __restrict__ out2, const float* __restrict__ a2,
    const float* __restrict__ g2, const float* __restrict__ b2,
    const int* __restrict__ acc2, uint32_t* __restrict__ xb2) {
  int m = blockIdx.x*256 + threadIdx.x;   // n*S2 + hw
  int wdx = blockIdx.y;                   // 0..7
  int n = m / S2, hw = m % S2;
  uint32_t p = 0, q = 0;
  #pragma unroll
  for (int j = 0; j < 32; ++j) {
    int c = wdx*32 + j;
    float av = a2[c], sc, sh;
    bn_finalize(acc2 + c*4, av, g2[c], b2[c], 1.f/NS2, sc, sh);
    float f = (float)out2[(size_t)(n*COUT + c)*S2 + hw];
    float pr = f > 0.f ? f : av*f;
    float tv = pr*sc + sh;
    p |= (uint32_t)(tv > 0.f) << j;
    q |= (uint32_t)(tv < 0.f) << j;
  }
  xb2[(size_t)m*16 + wdx    ] = p;
  xb2[(size_t)m*16 + 8 + wdx] = q;
}

// ---------------- conv3: binary 1x1 256->256 ----------------
__global__ __launch_bounds__(256) void conv3_kernel(
    const uint32_t* __restrict__ xb2, const uint32_t* __restrict__ wb3,
    int16_t* __restrict__ out3) {
  int m = blockIdx.x*256 + threadIdx.x;   // NS2
  int n = m / S2, hw = m % S2;
  const uint32_t* xw = xb2 + (size_t)m*16;
  uint32_t P[8], Q[8];
  #pragma unroll
  for (int i = 0; i < 8; ++i) { P[i] = xw[i]; Q[i] = xw[8+i]; }
  int co0 = blockIdx.y * 32;
  size_t obase = ((size_t)n*COUT)*S2 + hw;
  #pragma unroll 2
  for (int co = co0; co < co0 + 32; ++co) {
    const uint32_t* w = wb3 + (size_t)co*16;
    int acc = 0;
    #pragma unroll
    for (int i = 0; i < 8; ++i) {
      uint32_t wp = w[i], wn = w[8+i];
      acc += __popc(P[i]&wp) + __popc(Q[i]&wn) - __popc(P[i]&wn) - __popc(Q[i]&wp);
    }
    out3[obase + (size_t)co*S2] = (int16_t)acc;
  }
}

// ---------------- final: BN3(prelu(out3)) + residual ----------------
__global__ __launch_bounds__(256) void final_kernel(
    const int16_t* __restrict__ out3, const float* __restrict__ res,
    const float* __restrict__ a3, const float* __restrict__ g3,
    const float* __restrict__ b3, const int* __restrict__ acc3,
    float* __restrict__ out) {
  int idx = blockIdx.x*256 + threadIdx.x;
  int co = (idx / S2) % COUT;
  float av = a3[co], sc, sh;
  bn_finalize(acc3 + co*4, av, g3[co], b3[co], 1.f/NS2, sc, sh);
  float f = (float)out3[idx];
  float p = f > 0.f ? f : av*f;
  float t = p*sc + sh;
  out[idx] = t + res[idx];
}

extern "C" void kernel_launch(void* const* d_in, const int* in_sizes, int n_in,
                              void* d_out, int out_size, void* d_ws, size_t ws_size,
                              hipStream_t stream) {
  (void)in_sizes; (void)n_in; (void)out_size; (void)ws_size;
  const float* x    = (const float*)d_in[0];
  const float* w1   = (const float*)d_in[1];
  const float* a1   = (const float*)d_in[2];
  const float* g1   = (const float*)d_in[3];
  const float* b1   = (const float*)d_in[4];
  const float* wdw  = (const float*)d_in[5];
  const float* a2   = (const float*)d_in[6];
  const float* g2   = (const float*)d_in[7];
  const float* b2   = (const float*)d_in[8];
  const float* w3   = (const float*)d_in[9];
  const float* a3   = (const float*)d_in[10];
  const float* g3   = (const float*)d_in[11];
  const float* b3   = (const float*)d_in[12];
  const float* wadj = (const float*)d_in[13];
  float* out = (float*)d_out;

  char* ws = (char*)d_ws;
  uint32_t* xbits = (uint32_t*)(ws + OFF_XBITS);
  uint32_t* wb1   = (uint32_t*)(ws + OFF_WB1);
  uint32_t* wb3   = (uint32_t*)(ws + OFF_WB3);
  int8_t*   wdws  = (int8_t*)  (ws + OFF_WDW);
  int*      acc1  = (int*)     (ws + OFF_ACC);
  int*      acc2  = acc1 + 256*4;
  int*      acc3  = acc2 + 256*4;
  int8_t*   out1  = (int8_t*)  (ws + OFF_OUT1);
  float*    res   = (float*)   (ws + OFF_RES);
  int8_t*   out2  = (int8_t*)  (ws + OFF_OUT2);
  uint32_t* xb2   = (uint32_t*)(ws + OFF_XB2);
  int16_t*  out3  = (int16_t*) (ws + OFF_OUT3);

  hipMemsetAsync(acc1, 0, 3*256*4*sizeof(int), stream);
  packw_kernel<<<256, 64, 0, stream>>>(w1, w3, wdw, wb1, wb3, wdws);
  packx_kernel<<<dim3(NS1/256, 4), 256, 0, stream>>>(x, xbits);
  residual_kernel<<<dim3(NS2/256, COUT/8), 64, 0, stream>>>(x, wadj, res);
  conv1_kernel<<<dim3(NS1/256, 8), 256, 0, stream>>>(xbits, wb1, out1);
  // out1 stats: NS1/4=25088 quads per channel, 8 slices of 3136
  stats_i8_kernel<<<dim3(256, 8), 256, 0, stream>>>(out1, acc1, S1, 3136);
  dw_kernel<<<TOT2/256, 256, 0, stream>>>(out1, wdws, a1, g1, b1, acc1, out2);
  // out2 stats: NS2/4=6272 quads per channel, 4 slices of 1568
  stats_i8_kernel<<<dim3(256, 4), 256, 0, stream>>>(out2, acc2, S2, 1568);
  pack2_kernel<<<dim3(NS2/256, 8), 256, 0, stream>>>(out2, a2, g2, b2, acc2, xb2);
  conv3_kernel<<<dim3(NS2/256, 8), 256, 0, stream>>>(xb2, wb3, out3);
  // out3 stats: NS2/2=12544 pairs per channel, 4 slices of 3136
  stats_i16_kernel<<<dim3(256, 4), 256, 0, stream>>>(out3, acc3, S2, 3136);
  final_kernel<<<TOT2/256, 256, 0, stream>>>(out3, res, a3, g3, b3, acc3, out);
}

// Round 3
// 247.352 us; speedup vs baseline: 1.5944x; 1.0532x over previous
//
#include <hip/hip_runtime.h>
#include <stdint.h>

// ---- problem dims ----
#define NB   32
#define CIN  128
#define COUT 256
#define HH   56
#define WW   56
#define S1   (HH*WW)      // 3136
#define HO   28
#define WO   28
#define S2   (HO*WO)      // 784
#define NS1  (NB*S1)      // 100352
#define NS2  (NB*S2)      // 25088
#define TOT2 (NS2*COUT)   // 6422528
#define EPSV 1e-5f

// ---- workspace layout (bytes) ----
constexpr size_t OFF_XBITS = 0;                                 // NS1*8*4 = 3,211,264
constexpr size_t OFF_WB1   = OFF_XBITS + (size_t)NS1*8*4;       // 8 KB
constexpr size_t OFF_WB3   = OFF_WB1 + 256*8*4;                 // 16 KB
constexpr size_t OFF_WDW   = OFF_WB3 + 256*16*4;                // 4 KB
constexpr size_t OFF_ACC   = OFF_WDW + 4096;                    // 3*256*4 int = 12 KB
constexpr size_t OFF_OUT1  = OFF_ACC + 3*256*4*sizeof(int);     // NS1*COUT i8 = 25,690,112
constexpr size_t OFF_OUT2  = OFF_OUT1 + (size_t)NS1*COUT;       // i8 6,422,528
constexpr size_t OFF_XB2   = OFF_OUT2 + (size_t)TOT2;           // NS2*16*4 = 1,605,632
constexpr size_t OFF_OUT3  = OFF_XB2 + (size_t)NS2*16*4;        // i16 12,845,056
// total ~50 MB

// finalize BN scale/shift from exact integer sums of prelu output
__device__ __forceinline__ void bn_finalize(const int* __restrict__ acc4,
                                            float a, float g, float b, float inv_ns,
                                            float& sc, float& sh) {
  float ps = (float)acc4[0];   // sum of v where v>0
  float ng = (float)acc4[1];   // sum of v where v<0
  float pq = (float)acc4[2];   // sum of v^2 where v>0
  float nq = (float)acc4[3];   // sum of v^2 where v<0
  float mean = (ps + a*ng) * inv_ns;
  float ex2  = (pq + a*a*nq) * inv_ns;
  float var  = ex2 - mean*mean;
  float rs   = rsqrtf(var + EPSV);
  sc = rs * g;
  sh = b - mean * sc;
}

// ---------------- pack weights: bitplanes + dw signs ----------------
__global__ __launch_bounds__(64) void packw_kernel(
    const float* __restrict__ w1, const float* __restrict__ w3,
    const float* __restrict__ wdw,
    uint32_t* __restrict__ wb1, uint32_t* __restrict__ wb3,
    int8_t* __restrict__ wdws) {
  int co = blockIdx.x;
  int l  = threadIdx.x;
  for (int h = 0; h < 2; ++h) {
    float v = w1[(size_t)co*CIN + h*64 + l];
    unsigned long long bp = __ballot(v > 0.f);
    unsigned long long bn = __ballot(v < 0.f);
    if (l == 0) {
      wb1[co*8 + 2*h    ] = (uint32_t)bp;
      wb1[co*8 + 2*h + 1] = (uint32_t)(bp >> 32);
      wb1[co*8 + 4 + 2*h    ] = (uint32_t)bn;
      wb1[co*8 + 4 + 2*h + 1] = (uint32_t)(bn >> 32);
    }
  }
  for (int h = 0; h < 4; ++h) {
    float v = w3[(size_t)co*COUT + h*64 + l];
    unsigned long long bp = __ballot(v > 0.f);
    unsigned long long bn = __ballot(v < 0.f);
    if (l == 0) {
      wb3[co*16 + 2*h    ] = (uint32_t)bp;
      wb3[co*16 + 2*h + 1] = (uint32_t)(bp >> 32);
      wb3[co*16 + 8 + 2*h    ] = (uint32_t)bn;
      wb3[co*16 + 8 + 2*h + 1] = (uint32_t)(bn >> 32);
    }
  }
  if (l < 9) {
    float v = wdw[co*9 + l];
    wdws[co*9 + l] = (int8_t)((v > 0.f) - (v < 0.f));
  }
}

// ---------------- pack x into bitplanes over C (split over wdx) ----------------
__global__ __launch_bounds__(256) void packx_kernel(
    const float* __restrict__ x, uint32_t* __restrict__ xbits) {
  int m = blockIdx.x*256 + threadIdx.x;     // m = n*S1 + hw
  int wdx = blockIdx.y;                     // 0..3
  int n = m / S1, hw = m % S1;
  size_t base = ((size_t)n*CIN + wdx*32)*S1 + hw;
  uint32_t p = 0, q = 0;
  #pragma unroll
  for (int j = 0; j < 32; ++j) {
    float v = x[base + (size_t)j*S1];
    p |= (uint32_t)(v > 0.f) << j;
    q |= (uint32_t)(v < 0.f) << j;
  }
  xbits[(size_t)m*8 + wdx    ] = p;
  xbits[(size_t)m*8 + 4 + wdx] = q;
}

// ---------------- conv1: binary 1x1 via bitplane popcount ----------------
__global__ __launch_bounds__(256) void conv1_kernel(
    const uint32_t* __restrict__ xb, const uint32_t* __restrict__ wb,
    int8_t* __restrict__ out1) {
  int m = blockIdx.x*256 + threadIdx.x;
  int n = m / S1, hw = m % S1;
  const uint32_t* xw = xb + (size_t)m*8;
  uint32_t p0 = xw[0], p1 = xw[1], p2 = xw[2], p3 = xw[3];
  uint32_t q0 = xw[4], q1 = xw[5], q2 = xw[6], q3 = xw[7];
  int co0 = blockIdx.y * 32;
  size_t obase = ((size_t)n*COUT)*S1 + hw;
  #pragma unroll 4
  for (int co = co0; co < co0 + 32; ++co) {
    const uint32_t* w8 = wb + (size_t)co*8;
    uint32_t a0 = w8[0], a1 = w8[1], a2 = w8[2], a3 = w8[3];
    uint32_t b0 = w8[4], b1 = w8[5], b2 = w8[6], b3 = w8[7];
    int acc = __popc(p0&a0) + __popc(p1&a1) + __popc(p2&a2) + __popc(p3&a3)
            + __popc(q0&b0) + __popc(q1&b1) + __popc(q2&b2) + __popc(q3&b3)
            - __popc(p0&b0) - __popc(p1&b1) - __popc(p2&b2) - __popc(p3&b3)
            - __popc(q0&a0) - __popc(q1&a1) - __popc(q2&a2) - __popc(q3&a3);
    if (acc > 127) acc = 127;   // +128 would wrap int8; prob ~2^-128
    out1[obase + (size_t)co*S1] = (int8_t)acc;
  }
}

// ---------------- per-channel integer stats (int8 buffer) ----------------
__global__ __launch_bounds__(256) void stats_i8_kernel(
    const int8_t* __restrict__ buf, int* __restrict__ accum,
    int s_sp, int quads_per_block) {
  int co = blockIdx.x, slice = blockIdx.y;
  int q0 = slice * quads_per_block;
  int psum = 0, nsum = 0, psq = 0, nsq = 0;
  for (int i = threadIdx.x; i < quads_per_block; i += 256) {
    int flat = (q0 + i) * 4;
    int n = flat / s_sp, hw = flat % s_sp;
    char4 v = *reinterpret_cast<const char4*>(buf + (size_t)(n*COUT + co)*s_sp + hw);
    int vs[4] = {v.x, v.y, v.z, v.w};
    #pragma unroll
    for (int k = 0; k < 4; ++k) {
      int f = vs[k];
      if (f > 0) { psum += f; psq += f*f; } else { nsum += f; nsq += f*f; }
    }
  }
  __shared__ int r0[256], r1[256], r2[256], r3[256];
  int t = threadIdx.x;
  r0[t] = psum; r1[t] = nsum; r2[t] = psq; r3[t] = nsq;
  __syncthreads();
  for (int s = 128; s > 0; s >>= 1) {
    if (t < s) { r0[t]+=r0[t+s]; r1[t]+=r1[t+s]; r2[t]+=r2[t+s]; r3[t]+=r3[t+s]; }
    __syncthreads();
  }
  if (t == 0) {
    atomicAdd(&accum[co*4+0], r0[0]);
    atomicAdd(&accum[co*4+1], r1[0]);
    atomicAdd(&accum[co*4+2], r2[0]);
    atomicAdd(&accum[co*4+3], r3[0]);
  }
}

__global__ __launch_bounds__(256) void stats_i16_kernel(
    const int16_t* __restrict__ buf, int* __restrict__ accum,
    int s_sp, int pairs_per_block) {
  int co = blockIdx.x, slice = blockIdx.y;
  int p0i = slice * pairs_per_block;
  int psum = 0, nsum = 0, psq = 0, nsq = 0;
  for (int i = threadIdx.x; i < pairs_per_block; i += 256) {
    int flat = (p0i + i) * 2;
    int n = flat / s_sp, hw = flat % s_sp;
    short2 v = *reinterpret_cast<const short2*>(buf + (size_t)(n*COUT + co)*s_sp + hw);
    int vs[2] = {v.x, v.y};
    #pragma unroll
    for (int k = 0; k < 2; ++k) {
      int f = vs[k];
      if (f > 0) { psum += f; psq += f*f; } else { nsum += f; nsq += f*f; }
    }
  }
  __shared__ int r0[256], r1[256], r2[256], r3[256];
  int t = threadIdx.x;
  r0[t] = psum; r1[t] = nsum; r2[t] = psq; r3[t] = nsq;
  __syncthreads();
  for (int s = 128; s > 0; s >>= 1) {
    if (t < s) { r0[t]+=r0[t+s]; r1[t]+=r1[t+s]; r2[t]+=r2[t+s]; r3[t]+=r3[t+s]; }
    __syncthreads();
  }
  if (t == 0) {
    atomicAdd(&accum[co*4+0], r0[0]);
    atomicAdd(&accum[co*4+1], r1[0]);
    atomicAdd(&accum[co*4+2], r2[0]);
    atomicAdd(&accum[co*4+3], r3[0]);
  }
}

// ---------------- depthwise 3x3 s2 p1 on sign(BN1(prelu(out1))) ----------------
__global__ __launch_bounds__(256) void dw_kernel(
    const int8_t* __restrict__ out1, const int8_t* __restrict__ wdws,
    const float* __restrict__ a1, const float* __restrict__ g1,
    const float* __restrict__ b1, const int* __restrict__ acc1,
    int8_t* __restrict__ out2) {
  int idx = blockIdx.x*256 + threadIdx.x;   // over TOT2
  int hw2 = idx % S2;
  int nc  = idx / S2;           // n*COUT + co
  int co  = nc % COUT;
  int ho = hw2 / WO, wo = hw2 % WO;
  float av = a1[co], sc, sh;
  bn_finalize(acc1 + co*4, av, g1[co], b1[co], 1.f/NS1, sc, sh);
  const int8_t* src = out1 + (size_t)nc * S1;
  int acc = 0;
  #pragma unroll
  for (int kh = 0; kh < 3; ++kh) {
    int ih = 2*ho - 1 + kh;
    if (ih < 0 || ih >= HH) continue;
    #pragma unroll
    for (int kw = 0; kw < 3; ++kw) {
      int iw = 2*wo - 1 + kw;
      if (iw < 0 || iw >= WW) continue;
      float f = (float)src[ih*WW + iw];
      float p = f > 0.f ? f : av*f;
      float tv = p*sc + sh;
      int s = (tv > 0.f) - (tv < 0.f);
      acc += s * (int)wdws[co*9 + kh*3 + kw];
    }
  }
  out2[idx] = (int8_t)acc;
}

// ---------------- pack sign(BN2(prelu(out2))), split over wdx ----------------
__global__ __launch_bounds__(256) void pack2_kernel(
    const int8_t* __restrict__ out2, const float* __restrict__ a2,
    const float* __restrict__ g2, const float* __restrict__ b2,
    const int* __restrict__ acc2, uint32_t* __restrict__ xb2) {
  int m = blockIdx.x*256 + threadIdx.x;   // n*S2 + hw
  int wdx = blockIdx.y;                   // 0..7
  int n = m / S2, hw = m % S2;
  uint32_t p = 0, q = 0;
  #pragma unroll
  for (int j = 0; j < 32; ++j) {
    int c = wdx*32 + j;
    float av = a2[c], sc, sh;
    bn_finalize(acc2 + c*4, av, g2[c], b2[c], 1.f/NS2, sc, sh);
    float f = (float)out2[(size_t)(n*COUT + c)*S2 + hw];
    float pr = f > 0.f ? f : av*f;
    float tv = pr*sc + sh;
    p |= (uint32_t)(tv > 0.f) << j;
    q |= (uint32_t)(tv < 0.f) << j;
  }
  xb2[(size_t)m*16 + wdx    ] = p;
  xb2[(size_t)m*16 + 8 + wdx] = q;
}

// ---------------- conv3: binary 1x1 256->256 ----------------
__global__ __launch_bounds__(256) void conv3_kernel(
    const uint32_t* __restrict__ xb2, const uint32_t* __restrict__ wb3,
    int16_t* __restrict__ out3) {
  int m = blockIdx.x*256 + threadIdx.x;   // NS2
  int n = m / S2, hw = m % S2;
  const uint32_t* xw = xb2 + (size_t)m*16;
  uint32_t P[8], Q[8];
  #pragma unroll
  for (int i = 0; i < 8; ++i) { P[i] = xw[i]; Q[i] = xw[8+i]; }
  int co0 = blockIdx.y * 32;
  size_t obase = ((size_t)n*COUT)*S2 + hw;
  #pragma unroll 2
  for (int co = co0; co < co0 + 32; ++co) {
    const uint32_t* w = wb3 + (size_t)co*16;
    int acc = 0;
    #pragma unroll
    for (int i = 0; i < 8; ++i) {
      uint32_t wp = w[i], wn = w[8+i];
      acc += __popc(P[i]&wp) + __popc(Q[i]&wn) - __popc(P[i]&wn) - __popc(Q[i]&wp);
    }
    out3[obase + (size_t)co*S2] = (int16_t)acc;
  }
}

// ---------------- fused residual (fp32 1x1 s2) + BN3(prelu(out3)) + add ----------------
// block = 512 threads; tile = 64 m positions x ALL 256 co -> x read exactly once.
// thread t: m_local = t & 63, co group = (t >> 6)*32 .. +31 (32 accumulators)
#define TILE_M 64
__global__ __launch_bounds__(512) void resfinal_kernel(
    const float* __restrict__ x, const float* __restrict__ wadj,
    const int16_t* __restrict__ out3,
    const float* __restrict__ a3, const float* __restrict__ g3,
    const float* __restrict__ b3, const int* __restrict__ acc3,
    float* __restrict__ out) {
  __shared__ float xt[CIN][TILE_M];      // 32 KB
  __shared__ float scs[COUT], shs[COUT]; // 2 KB
  int tid = threadIdx.x;
  int m0 = blockIdx.x * TILE_M;

  if (tid < COUT) {
    float sc, sh;
    bn_finalize(acc3 + tid*4, a3[tid], g3[tid], b3[tid], 1.f/NS2, sc, sh);
    scs[tid] = sc; shs[tid] = sh;
  }
  // load x tile: 128 c x 64 m, 16 elements per thread; wave reads one c-row
  #pragma unroll
  for (int k = 0; k < 16; ++k) {
    int idx = k*512 + tid;
    int c  = idx >> 6;
    int ml = idx & 63;
    int m = m0 + ml;
    int n = m / S2, hw = m % S2;
    int ho = hw / WO, wo = hw % WO;
    xt[c][ml] = x[((size_t)n*CIN + c)*S1 + (size_t)(2*ho)*WW + 2*wo];
  }
  __syncthreads();

  int ml  = tid & 63;
  int cg  = __builtin_amdgcn_readfirstlane(tid >> 6);  // wave-uniform 0..7
  int co0 = cg * 32;
  const float* wbase = wadj + (size_t)co0 * CIN;

  float acc[32];
  #pragma unroll
  for (int j = 0; j < 32; ++j) acc[j] = 0.f;

  #pragma unroll 4
  for (int c = 0; c < CIN; ++c) {
    float xv = xt[c][ml];
    #pragma unroll
    for (int j = 0; j < 32; ++j)
      acc[j] = fmaf(xv, wbase[(size_t)j*CIN + c], acc[j]);
  }

  // epilogue: t = BN3(prelu(out3)) + residual
  int m = m0 + ml;
  int n = m / S2, hw = m % S2;
  size_t obase = ((size_t)n*COUT + co0)*S2 + hw;
  #pragma unroll
  for (int j = 0; j < 32; ++j) {
    int co = co0 + j;
    float f = (float)out3[obase + (size_t)j*S2];
    float p = f > 0.f ? f : a3[co]*f;
    float t = p*scs[co] + shs[co];
    out[obase + (size_t)j*S2] = t + acc[j];
  }
}

extern "C" void kernel_launch(void* const* d_in, const int* in_sizes, int n_in,
                              void* d_out, int out_size, void* d_ws, size_t ws_size,
                              hipStream_t stream) {
  (void)in_sizes; (void)n_in; (void)out_size; (void)ws_size;
  const float* x    = (const float*)d_in[0];
  const float* w1   = (const float*)d_in[1];
  const float* a1   = (const float*)d_in[2];
  const float* g1   = (const float*)d_in[3];
  const float* b1   = (const float*)d_in[4];
  const float* wdw  = (const float*)d_in[5];
  const float* a2   = (const float*)d_in[6];
  const float* g2   = (const float*)d_in[7];
  const float* b2   = (const float*)d_in[8];
  const float* w3   = (const float*)d_in[9];
  const float* a3   = (const float*)d_in[10];
  const float* g3   = (const float*)d_in[11];
  const float* b3   = (const float*)d_in[12];
  const float* wadj = (const float*)d_in[13];
  float* out = (float*)d_out;

  char* ws = (char*)d_ws;
  uint32_t* xbits = (uint32_t*)(ws + OFF_XBITS);
  uint32_t* wb1   = (uint32_t*)(ws + OFF_WB1);
  uint32_t* wb3   = (uint32_t*)(ws + OFF_WB3);
  int8_t*   wdws  = (int8_t*)  (ws + OFF_WDW);
  int*      acc1  = (int*)     (ws + OFF_ACC);
  int*      acc2  = acc1 + 256*4;
  int*      acc3  = acc2 + 256*4;
  int8_t*   out1  = (int8_t*)  (ws + OFF_OUT1);
  int8_t*   out2  = (int8_t*)  (ws + OFF_OUT2);
  uint32_t* xb2   = (uint32_t*)(ws + OFF_XB2);
  int16_t*  out3  = (int16_t*) (ws + OFF_OUT3);

  hipMemsetAsync(acc1, 0, 3*256*4*sizeof(int), stream);
  packw_kernel<<<256, 64, 0, stream>>>(w1, w3, wdw, wb1, wb3, wdws);
  packx_kernel<<<dim3(NS1/256, 4), 256, 0, stream>>>(x, xbits);
  conv1_kernel<<<dim3(NS1/256, 8), 256, 0, stream>>>(xbits, wb1, out1);
  stats_i8_kernel<<<dim3(256, 8), 256, 0, stream>>>(out1, acc1, S1, 3136);
  dw_kernel<<<TOT2/256, 256, 0, stream>>>(out1, wdws, a1, g1, b1, acc1, out2);
  stats_i8_kernel<<<dim3(256, 4), 256, 0, stream>>>(out2, acc2, S2, 1568);
  pack2_kernel<<<dim3(NS2/256, 8), 256, 0, stream>>>(out2, a2, g2, b2, acc2, xb2);
  conv3_kernel<<<dim3(NS2/256, 8), 256, 0, stream>>>(xb2, wb3, out3);
  stats_i16_kernel<<<dim3(256, 4), 256, 0, stream>>>(out3, acc3, S2, 3136);
  resfinal_kernel<<<NS2/TILE_M, 512, 0, stream>>>(x, wadj, out3, a3, g3, b3, acc3, out);
}

// Round 4
// 206.068 us; speedup vs baseline: 1.9138x; 1.2003x over previous
//
#include <hip/hip_runtime.h>
#include <stdint.h>

// ---- problem dims ----
#define NB   32
#define CIN  128
#define COUT 256
#define HH   56
#define WW   56
#define S1   (HH*WW)      // 3136
#define HO   28
#define WO   28
#define S2   (HO*WO)      // 784
#define NS1  (NB*S1)      // 100352
#define NS2  (NB*S2)      // 25088
#define TOT2 (NS2*COUT)   // 6422528
#define EPSV 1e-5f

// ---- workspace layout (bytes) ----
constexpr size_t OFF_XBITS = 0;                                 // NS1*8*4 = 3,211,264
constexpr size_t OFF_WB1   = OFF_XBITS + (size_t)NS1*8*4;       // 8 KB
constexpr size_t OFF_WB3   = OFF_WB1 + 256*8*4;                 // 16 KB
constexpr size_t OFF_WDW   = OFF_WB3 + 256*16*4;                // 4 KB
constexpr size_t OFF_ACC   = OFF_WDW + 4096;                    // 3*256*4 int = 12 KB
constexpr size_t OFF_WADJT = OFF_ACC + 3*256*4*sizeof(int);     // 128*256*4 = 131,072
constexpr size_t OFF_OUT1  = OFF_WADJT + (size_t)CIN*COUT*4;    // NS1*COUT i8 = 25,690,112
constexpr size_t OFF_OUT2  = OFF_OUT1 + (size_t)NS1*COUT;       // i8 6,422,528
constexpr size_t OFF_XB2   = OFF_OUT2 + (size_t)TOT2;           // NS2*16*4 = 1,605,632
constexpr size_t OFF_OUT3  = OFF_XB2 + (size_t)NS2*16*4;        // i16 12,845,056
// total ~50 MB

// finalize BN scale/shift from exact integer sums of prelu output
__device__ __forceinline__ void bn_finalize(const int* __restrict__ acc4,
                                            float a, float g, float b, float inv_ns,
                                            float& sc, float& sh) {
  float ps = (float)acc4[0];   // sum of v where v>0
  float ng = (float)acc4[1];   // sum of v where v<0
  float pq = (float)acc4[2];   // sum of v^2 where v>0
  float nq = (float)acc4[3];   // sum of v^2 where v<0
  float mean = (ps + a*ng) * inv_ns;
  float ex2  = (pq + a*a*nq) * inv_ns;
  float var  = ex2 - mean*mean;
  float rs   = rsqrtf(var + EPSV);
  sc = rs * g;
  sh = b - mean * sc;
}

// ---------------- pack weights: bitplanes + dw signs + wadj transpose ----------------
__global__ __launch_bounds__(64) void packw_kernel(
    const float* __restrict__ w1, const float* __restrict__ w3,
    const float* __restrict__ wdw, const float* __restrict__ wadj,
    uint32_t* __restrict__ wb1, uint32_t* __restrict__ wb3,
    int8_t* __restrict__ wdws, float* __restrict__ wadjT) {
  int co = blockIdx.x;
  int l  = threadIdx.x;
  for (int h = 0; h < 2; ++h) {
    float v = w1[(size_t)co*CIN + h*64 + l];
    unsigned long long bp = __ballot(v > 0.f);
    unsigned long long bn = __ballot(v < 0.f);
    if (l == 0) {
      wb1[co*8 + 2*h    ] = (uint32_t)bp;
      wb1[co*8 + 2*h + 1] = (uint32_t)(bp >> 32);
      wb1[co*8 + 4 + 2*h    ] = (uint32_t)bn;
      wb1[co*8 + 4 + 2*h + 1] = (uint32_t)(bn >> 32);
    }
  }
  for (int h = 0; h < 4; ++h) {
    float v = w3[(size_t)co*COUT + h*64 + l];
    unsigned long long bp = __ballot(v > 0.f);
    unsigned long long bn = __ballot(v < 0.f);
    if (l == 0) {
      wb3[co*16 + 2*h    ] = (uint32_t)bp;
      wb3[co*16 + 2*h + 1] = (uint32_t)(bp >> 32);
      wb3[co*16 + 8 + 2*h    ] = (uint32_t)bn;
      wb3[co*16 + 8 + 2*h + 1] = (uint32_t)(bn >> 32);
    }
  }
  if (l < 9) {
    float v = wdw[co*9 + l];
    wdws[co*9 + l] = (int8_t)((v > 0.f) - (v < 0.f));
  }
  // transpose w_adj: wadjT[c][co] = wadj[co][c]
  #pragma unroll
  for (int k = 0; k < 2; ++k) {
    int c = 2*l + k;
    wadjT[(size_t)c*COUT + co] = wadj[(size_t)co*CIN + c];
  }
}

// ---------------- pack x into bitplanes over C (split over wdx) ----------------
__global__ __launch_bounds__(256) void packx_kernel(
    const float* __restrict__ x, uint32_t* __restrict__ xbits) {
  int m = blockIdx.x*256 + threadIdx.x;     // m = n*S1 + hw
  int wdx = blockIdx.y;                     // 0..3
  int n = m / S1, hw = m % S1;
  size_t base = ((size_t)n*CIN + wdx*32)*S1 + hw;
  uint32_t p = 0, q = 0;
  #pragma unroll
  for (int j = 0; j < 32; ++j) {
    float v = x[base + (size_t)j*S1];
    p |= (uint32_t)(v > 0.f) << j;
    q |= (uint32_t)(v < 0.f) << j;
  }
  xbits[(size_t)m*8 + wdx    ] = p;
  xbits[(size_t)m*8 + 4 + wdx] = q;
}

// ---------------- conv1: binary 1x1 via bitplane popcount ----------------
__global__ __launch_bounds__(256) void conv1_kernel(
    const uint32_t* __restrict__ xb, const uint32_t* __restrict__ wb,
    int8_t* __restrict__ out1) {
  int m = blockIdx.x*256 + threadIdx.x;
  int n = m / S1, hw = m % S1;
  const uint32_t* xw = xb + (size_t)m*8;
  uint32_t p0 = xw[0], p1 = xw[1], p2 = xw[2], p3 = xw[3];
  uint32_t q0 = xw[4], q1 = xw[5], q2 = xw[6], q3 = xw[7];
  int co0 = blockIdx.y * 32;
  size_t obase = ((size_t)n*COUT)*S1 + hw;
  #pragma unroll 4
  for (int co = co0; co < co0 + 32; ++co) {
    const uint32_t* w8 = wb + (size_t)co*8;
    uint32_t a0 = w8[0], a1 = w8[1], a2 = w8[2], a3 = w8[3];
    uint32_t b0 = w8[4], b1 = w8[5], b2 = w8[6], b3 = w8[7];
    int acc = __popc(p0&a0) + __popc(p1&a1) + __popc(p2&a2) + __popc(p3&a3)
            + __popc(q0&b0) + __popc(q1&b1) + __popc(q2&b2) + __popc(q3&b3)
            - __popc(p0&b0) - __popc(p1&b1) - __popc(p2&b2) - __popc(p3&b3)
            - __popc(q0&a0) - __popc(q1&a1) - __popc(q2&a2) - __popc(q3&a3);
    if (acc > 127) acc = 127;   // +128 would wrap int8; prob ~2^-128
    out1[obase + (size_t)co*S1] = (int8_t)acc;
  }
}

// ---------------- per-channel integer stats (int8 buffer) ----------------
__global__ __launch_bounds__(256) void stats_i8_kernel(
    const int8_t* __restrict__ buf, int* __restrict__ accum,
    int s_sp, int quads_per_block) {
  int co = blockIdx.x, slice = blockIdx.y;
  int q0 = slice * quads_per_block;
  int psum = 0, nsum = 0, psq = 0, nsq = 0;
  for (int i = threadIdx.x; i < quads_per_block; i += 256) {
    int flat = (q0 + i) * 4;
    int n = flat / s_sp, hw = flat % s_sp;
    char4 v = *reinterpret_cast<const char4*>(buf + (size_t)(n*COUT + co)*s_sp + hw);
    int vs[4] = {v.x, v.y, v.z, v.w};
    #pragma unroll
    for (int k = 0; k < 4; ++k) {
      int f = vs[k];
      if (f > 0) { psum += f; psq += f*f; } else { nsum += f; nsq += f*f; }
    }
  }
  __shared__ int r0[256], r1[256], r2[256], r3[256];
  int t = threadIdx.x;
  r0[t] = psum; r1[t] = nsum; r2[t] = psq; r3[t] = nsq;
  __syncthreads();
  for (int s = 128; s > 0; s >>= 1) {
    if (t < s) { r0[t]+=r0[t+s]; r1[t]+=r1[t+s]; r2[t]+=r2[t+s]; r3[t]+=r3[t+s]; }
    __syncthreads();
  }
  if (t == 0) {
    atomicAdd(&accum[co*4+0], r0[0]);
    atomicAdd(&accum[co*4+1], r1[0]);
    atomicAdd(&accum[co*4+2], r2[0]);
    atomicAdd(&accum[co*4+3], r3[0]);
  }
}

__global__ __launch_bounds__(256) void stats_i16_kernel(
    const int16_t* __restrict__ buf, int* __restrict__ accum,
    int s_sp, int pairs_per_block) {
  int co = blockIdx.x, slice = blockIdx.y;
  int p0i = slice * pairs_per_block;
  int psum = 0, nsum = 0, psq = 0, nsq = 0;
  for (int i = threadIdx.x; i < pairs_per_block; i += 256) {
    int flat = (p0i + i) * 2;
    int n = flat / s_sp, hw = flat % s_sp;
    short2 v = *reinterpret_cast<const short2*>(buf + (size_t)(n*COUT + co)*s_sp + hw);
    int vs[2] = {v.x, v.y};
    #pragma unroll
    for (int k = 0; k < 2; ++k) {
      int f = vs[k];
      if (f > 0) { psum += f; psq += f*f; } else { nsum += f; nsq += f*f; }
    }
  }
  __shared__ int r0[256], r1[256], r2[256], r3[256];
  int t = threadIdx.x;
  r0[t] = psum; r1[t] = nsum; r2[t] = psq; r3[t] = nsq;
  __syncthreads();
  for (int s = 128; s > 0; s >>= 1) {
    if (t < s) { r0[t]+=r0[t+s]; r1[t]+=r1[t+s]; r2[t]+=r2[t+s]; r3[t]+=r3[t+s]; }
    __syncthreads();
  }
  if (t == 0) {
    atomicAdd(&accum[co*4+0], r0[0]);
    atomicAdd(&accum[co*4+1], r1[0]);
    atomicAdd(&accum[co*4+2], r2[0]);
    atomicAdd(&accum[co*4+3], r3[0]);
  }
}

// ---------------- depthwise 3x3 s2 p1 on sign(BN1(prelu(out1))) ----------------
__global__ __launch_bounds__(256) void dw_kernel(
    const int8_t* __restrict__ out1, const int8_t* __restrict__ wdws,
    const float* __restrict__ a1, const float* __restrict__ g1,
    const float* __restrict__ b1, const int* __restrict__ acc1,
    int8_t* __restrict__ out2) {
  int idx = blockIdx.x*256 + threadIdx.x;   // over TOT2
  int hw2 = idx % S2;
  int nc  = idx / S2;           // n*COUT + co
  int co  = nc % COUT;
  int ho = hw2 / WO, wo = hw2 % WO;
  float av = a1[co], sc, sh;
  bn_finalize(acc1 + co*4, av, g1[co], b1[co], 1.f/NS1, sc, sh);
  const int8_t* src = out1 + (size_t)nc * S1;
  int acc = 0;
  #pragma unroll
  for (int kh = 0; kh < 3; ++kh) {
    int ih = 2*ho - 1 + kh;
    if (ih < 0 || ih >= HH) continue;
    #pragma unroll
    for (int kw = 0; kw < 3; ++kw) {
      int iw = 2*wo - 1 + kw;
      if (iw < 0 || iw >= WW) continue;
      float f = (float)src[ih*WW + iw];
      float p = f > 0.f ? f : av*f;
      float tv = p*sc + sh;
      int s = (tv > 0.f) - (tv < 0.f);
      acc += s * (int)wdws[co*9 + kh*3 + kw];
    }
  }
  out2[idx] = (int8_t)acc;
}

// ---------------- pack sign(BN2(prelu(out2))), split over wdx ----------------
__global__ __launch_bounds__(256) void pack2_kernel(
    const int8_t* __restrict__ out2, const float* __restrict__ a2,
    const float* __restrict__ g2, const float* __restrict__ b2,
    const int* __restrict__ acc2, uint32_t* __restrict__ xb2) {
  int m = blockIdx.x*256 + threadIdx.x;   // n*S2 + hw
  int wdx = blockIdx.y;                   // 0..7
  int n = m / S2, hw = m % S2;
  uint32_t p = 0, q = 0;
  #pragma unroll
  for (int j = 0; j < 32; ++j) {
    int c = wdx*32 + j;
    float av = a2[c], sc, sh;
    bn_finalize(acc2 + c*4, av, g2[c], b2[c], 1.f/NS2, sc, sh);
    float f = (float)out2[(size_t)(n*COUT + c)*S2 + hw];
    float pr = f > 0.f ? f : av*f;
    float tv = pr*sc + sh;
    p |= (uint32_t)(tv > 0.f) << j;
    q |= (uint32_t)(tv < 0.f) << j;
  }
  xb2[(size_t)m*16 + wdx    ] = p;
  xb2[(size_t)m*16 + 8 + wdx] = q;
}

// ---------------- conv3: binary 1x1 256->256 ----------------
__global__ __launch_bounds__(256) void conv3_kernel(
    const uint32_t* __restrict__ xb2, const uint32_t* __restrict__ wb3,
    int16_t* __restrict__ out3) {
  int m = blockIdx.x*256 + threadIdx.x;   // NS2
  int n = m / S2, hw = m % S2;
  const uint32_t* xw = xb2 + (size_t)m*16;
  uint32_t P[8], Q[8];
  #pragma unroll
  for (int i = 0; i < 8; ++i) { P[i] = xw[i]; Q[i] = xw[8+i]; }
  int co0 = blockIdx.y * 32;
  size_t obase = ((size_t)n*COUT)*S2 + hw;
  #pragma unroll 2
  for (int co = co0; co < co0 + 32; ++co) {
    const uint32_t* w = wb3 + (size_t)co*16;
    int acc = 0;
    #pragma unroll
    for (int i = 0; i < 8; ++i) {
      uint32_t wp = w[i], wn = w[8+i];
      acc += __popc(P[i]&wp) + __popc(Q[i]&wn) - __popc(P[i]&wn) - __popc(Q[i]&wp);
    }
    out3[obase + (size_t)co*S2] = (int16_t)acc;
  }
}

// ---------------- fused residual (fp32 1x1 s2) + BN3(prelu(out3)) + add ----------------
// grid (NS2/64, 2); block 512. Tile: 64 m x 128 co (half). Thread: 1 m x 16 co.
// Waves own a 16-co group -> weight loads are wave-uniform scalar loads from wadjT.
#define TILE_M 64
__global__ __launch_bounds__(512, 2) void resfinal_kernel(
    const float* __restrict__ x, const float* __restrict__ wadjT,
    const int16_t* __restrict__ out3,
    const float* __restrict__ a3, const float* __restrict__ g3,
    const float* __restrict__ b3, const int* __restrict__ acc3,
    float* __restrict__ out) {
  __shared__ float xt[CIN][TILE_M];                 // 32 KB
  __shared__ float scs[128], shs[128], avs[128];    // 1.5 KB
  int tid = threadIdx.x;
  int m0 = blockIdx.x * TILE_M;
  int coh = blockIdx.y * 128;

  if (tid < 128) {
    int co = coh + tid;
    float sc, sh;
    bn_finalize(acc3 + co*4, a3[co], g3[co], b3[co], 1.f/NS2, sc, sh);
    scs[tid] = sc; shs[tid] = sh; avs[tid] = a3[co];
  }
  // load x tile: 128 c x 64 m
  #pragma unroll
  for (int k = 0; k < 16; ++k) {
    int idx = k*512 + tid;
    int c  = idx >> 6;
    int ml = idx & 63;
    int m = m0 + ml;
    int n = m / S2, hw = m % S2;
    int ho = hw / WO, wo = hw % WO;
    xt[c][ml] = x[((size_t)n*CIN + c)*S1 + (size_t)(2*ho)*WW + 2*wo];
  }
  __syncthreads();

  int ml  = tid & 63;
  int cg  = __builtin_amdgcn_readfirstlane(tid >> 6);  // wave-uniform 0..7
  int col = cg * 16;                                    // local co base in half
  const float* wT = wadjT + coh + col;                  // wT[c*COUT + j], j<16 contiguous

  float acc[16];
  #pragma unroll
  for (int j = 0; j < 16; ++j) acc[j] = 0.f;

  #pragma unroll 2
  for (int c = 0; c < CIN; ++c) {
    float xv = xt[c][ml];
    #pragma unroll
    for (int j = 0; j < 16; ++j)
      acc[j] = fmaf(xv, wT[(size_t)c*COUT + j], acc[j]);
  }

  // epilogue: BN3(prelu(out3)) + residual
  int m = m0 + ml;
  int n = m / S2, hw = m % S2;
  size_t obase = ((size_t)n*COUT + coh + col)*S2 + hw;
  #pragma unroll
  for (int j = 0; j < 16; ++j) {
    int cl = col + j;
    float f = (float)out3[obase + (size_t)j*S2];
    float p = f > 0.f ? f : avs[cl]*f;
    float t = p*scs[cl] + shs[cl];
    out[obase + (size_t)j*S2] = t + acc[j];
  }
}

extern "C" void kernel_launch(void* const* d_in, const int* in_sizes, int n_in,
                              void* d_out, int out_size, void* d_ws, size_t ws_size,
                              hipStream_t stream) {
  (void)in_sizes; (void)n_in; (void)out_size; (void)ws_size;
  const float* x    = (const float*)d_in[0];
  const float* w1   = (const float*)d_in[1];
  const float* a1   = (const float*)d_in[2];
  const float* g1   = (const float*)d_in[3];
  const float* b1   = (const float*)d_in[4];
  const float* wdw  = (const float*)d_in[5];
  const float* a2   = (const float*)d_in[6];
  const float* g2   = (const float*)d_in[7];
  const float* b2   = (const float*)d_in[8];
  const float* w3   = (const float*)d_in[9];
  const float* a3   = (const float*)d_in[10];
  const float* g3   = (const float*)d_in[11];
  const float* b3   = (const float*)d_in[12];
  const float* wadj = (const float*)d_in[13];
  float* out = (float*)d_out;

  char* ws = (char*)d_ws;
  uint32_t* xbits = (uint32_t*)(ws + OFF_XBITS);
  uint32_t* wb1   = (uint32_t*)(ws + OFF_WB1);
  uint32_t* wb3   = (uint32_t*)(ws + OFF_WB3);
  int8_t*   wdws  = (int8_t*)  (ws + OFF_WDW);
  int*      acc1  = (int*)     (ws + OFF_ACC);
  int*      acc2  = acc1 + 256*4;
  int*      acc3  = acc2 + 256*4;
  float*    wadjT = (float*)   (ws + OFF_WADJT);
  int8_t*   out1  = (int8_t*)  (ws + OFF_OUT1);
  int8_t*   out2  = (int8_t*)  (ws + OFF_OUT2);
  uint32_t* xb2   = (uint32_t*)(ws + OFF_XB2);
  int16_t*  out3  = (int16_t*) (ws + OFF_OUT3);

  hipMemsetAsync(acc1, 0, 3*256*4*sizeof(int), stream);
  packw_kernel<<<256, 64, 0, stream>>>(w1, w3, wdw, wadj, wb1, wb3, wdws, wadjT);
  packx_kernel<<<dim3(NS1/256, 4), 256, 0, stream>>>(x, xbits);
  conv1_kernel<<<dim3(NS1/256, 8), 256, 0, stream>>>(xbits, wb1, out1);
  stats_i8_kernel<<<dim3(256, 8), 256, 0, stream>>>(out1, acc1, S1, 3136);
  dw_kernel<<<TOT2/256, 256, 0, stream>>>(out1, wdws, a1, g1, b1, acc1, out2);
  stats_i8_kernel<<<dim3(256, 4), 256, 0, stream>>>(out2, acc2, S2, 1568);
  pack2_kernel<<<dim3(NS2/256, 8), 256, 0, stream>>>(out2, a2, g2, b2, acc2, xb2);
  conv3_kernel<<<dim3(NS2/256, 8), 256, 0, stream>>>(xb2, wb3, out3);
  stats_i16_kernel<<<dim3(256, 4), 256, 0, stream>>>(out3, acc3, S2, 3136);
  resfinal_kernel<<<dim3(NS2/TILE_M, 2), 512, 0, stream>>>(x, wadjT, out3, a3, g3, b3, acc3, out);
}